// Round 3
// baseline (2957.018 us; speedup 1.0000x reference)
//
#include <hip/hip_runtime.h>
#include <hip/hip_bf16.h>

#define D_MODEL 2048
#define N_HEADS 16
#define D_HEAD 128
#define SEQ 2048
#define BATCH 2
#define M_ROWS (SEQ*BATCH)     // 4096
#define QKV_N  (3*D_MODEL)     // 6144

// 1/sqrt(D_HEAD) folded into Q in the RoPE epilogue
#define ATTN_SCALE 0.08838834764831845f

// ---------------------------------------------------------------------------
// NT GEMM core: C[m][n] = sum_k A[m][k] * B[n][k]
// BM=BN=128, BK=16, 256 threads, 8x8 micro-tile split in 4+4 quadrants.
// LDS is k-major (As[k][m]) so compute-phase reads are contiguous float4s.
// ---------------------------------------------------------------------------

// Kernel 1: QKV projection + bias + RoPE + scatter into (B,H,S,D) Q/K/V.
__global__ __launch_bounds__(256, 3) void qkv_rope_kernel(
    const float* __restrict__ X,      // (4096, 2048) rows = s*B+b
    const float* __restrict__ W,      // (6144, 2048)
    const float* __restrict__ bias,   // (6144)
    const float* __restrict__ freqs,  // (2048, 64)
    float* __restrict__ Qp, float* __restrict__ Kp, float* __restrict__ Vp)
{
    __shared__ float As[16][128];
    __shared__ float Bs[16][128];
    const int t  = threadIdx.x;
    const int tx = t & 15, ty = t >> 4;
    const int m0 = blockIdx.x * 128;
    const int n0 = blockIdx.y * 128;
    const int srow = t >> 1;          // 0..127
    const int sk   = (t & 1) * 8;     // 0 or 8

    const float* arow = X + (size_t)(m0 + srow) * D_MODEL + sk;
    const float* brow = W + (size_t)(n0 + srow) * D_MODEL + sk;

    float acc[8][8];
#pragma unroll
    for (int i = 0; i < 8; ++i)
#pragma unroll
        for (int j = 0; j < 8; ++j) acc[i][j] = 0.f;

    float4 a0 = *(const float4*)(arow);
    float4 a1 = *(const float4*)(arow + 4);
    float4 b0 = *(const float4*)(brow);
    float4 b1 = *(const float4*)(brow + 4);

    for (int k0 = 0; k0 < D_MODEL; k0 += 16) {
        __syncthreads();
        As[sk+0][srow] = a0.x; As[sk+1][srow] = a0.y; As[sk+2][srow] = a0.z; As[sk+3][srow] = a0.w;
        As[sk+4][srow] = a1.x; As[sk+5][srow] = a1.y; As[sk+6][srow] = a1.z; As[sk+7][srow] = a1.w;
        Bs[sk+0][srow] = b0.x; Bs[sk+1][srow] = b0.y; Bs[sk+2][srow] = b0.z; Bs[sk+3][srow] = b0.w;
        Bs[sk+4][srow] = b1.x; Bs[sk+5][srow] = b1.y; Bs[sk+6][srow] = b1.z; Bs[sk+7][srow] = b1.w;
        __syncthreads();
        if (k0 + 16 < D_MODEL) {   // prefetch next tile; latency hidden under compute
            a0 = *(const float4*)(arow + k0 + 16);
            a1 = *(const float4*)(arow + k0 + 20);
            b0 = *(const float4*)(brow + k0 + 16);
            b1 = *(const float4*)(brow + k0 + 20);
        }
#pragma unroll
        for (int kk = 0; kk < 16; ++kk) {
            float4 alo = *(const float4*)&As[kk][ty*4];
            float4 ahi = *(const float4*)&As[kk][64 + ty*4];
            float4 blo = *(const float4*)&Bs[kk][tx*4];
            float4 bhi = *(const float4*)&Bs[kk][64 + tx*4];
            float av[8] = {alo.x, alo.y, alo.z, alo.w, ahi.x, ahi.y, ahi.z, ahi.w};
            float bv[8] = {blo.x, blo.y, blo.z, blo.w, bhi.x, bhi.y, bhi.z, bhi.w};
#pragma unroll
            for (int i = 0; i < 8; ++i)
#pragma unroll
                for (int j = 0; j < 8; ++j)
                    acc[i][j] = fmaf(av[i], bv[j], acc[i][j]);
        }
    }

    // Epilogue: bias + RoPE (+scale into Q) + scatter to (B,H,S,D)
#pragma unroll
    for (int i = 0; i < 8; ++i) {
        const int m = m0 + ((i < 4) ? (ty*4 + i) : (64 + ty*4 + (i-4)));
        const int s = m >> 1, bb = m & 1;
#pragma unroll
        for (int jh = 0; jh < 2; ++jh) {
#pragma unroll
            for (int jp = 0; jp < 2; ++jp) {
                const int n  = n0 + jh*64 + tx*4 + jp*2;   // even
                const int ci = jh*4 + jp*2;
                float v0 = acc[i][ci]   + bias[n];
                float v1 = acc[i][ci+1] + bias[n+1];
                const int sec = n >> 11;
                const int e   = n & 2047;
                const int h   = e >> 7, d = e & 127;
                float* dst;
                if (sec == 2) {
                    dst = Vp + (((size_t)(bb*N_HEADS + h) * SEQ + s) * D_HEAD + d);
                    dst[0] = v0; dst[1] = v1;
                } else {
                    float fr = freqs[(size_t)s * 64 + (d >> 1)];
                    float sn, cs; sincosf(fr, &sn, &cs);
                    float o0 = v0*cs - v1*sn;
                    float o1 = v0*sn + v1*cs;
                    if (sec == 0) { o0 *= ATTN_SCALE; o1 *= ATTN_SCALE; dst = Qp; }
                    else          { dst = Kp; }
                    dst += (((size_t)(bb*N_HEADS + h) * SEQ + s) * D_HEAD + d);
                    dst[0] = o0; dst[1] = o1;
                }
            }
        }
    }
}

// ---------------------------------------------------------------------------
// Kernel 2: causal flash attention, fp32.
// One block per (bh, 64-row q-tile). KV-tile = 32. 256 threads (16x16).
// LDS exactly 64 KiB: Q 64x128 f32 + K 32x128 + V 32x128, XOR-swizzled f4.
// Thread (tx,ty): score rows r=4ty+i (i<4), cols c=j*16+tx (j<2).
// O cols: float4 blocks {tx, 16+tx} -> cols tx*4..+3 and 64+tx*4..+3.
// P stays in registers; PV uses __shfl broadcast within 16-lane groups.
// ---------------------------------------------------------------------------
__global__ __launch_bounds__(256, 2) void attn_kernel(
    const float* __restrict__ Qp, const float* __restrict__ Kp,
    const float* __restrict__ Vp, float* __restrict__ Op /* (4096,2048) */)
{
    __shared__ float4 smem[4096];          // 64 KiB
    float4* Qs = smem;                     // 64*32
    float4* Ks = smem + 2048;              // 32*32
    float4* Vs = smem + 3072;              // 32*32

    const int t  = threadIdx.x;
    const int tx = t & 15, ty = t >> 4;
    const int qb = (int)gridDim.x - 1 - (int)blockIdx.x;   // big tiles first
    const int bh = blockIdx.y;
    const int q0 = qb * 64;
    const size_t headoff = (size_t)bh * SEQ * D_HEAD;

    // stage Q tile (swizzled)
#pragma unroll
    for (int i = 0; i < 8; ++i) {
        int f4 = i*256 + t;
        int r  = f4 >> 5, bd = f4 & 31;
        float4 v = *(const float4*)(Qp + headoff + (size_t)(q0 + r)*D_HEAD + bd*4);
        Qs[r*32 + (bd ^ (r & 7))] = v;
    }

    float o[4][8];
    float mrow[4], lrow[4];
#pragma unroll
    for (int i = 0; i < 4; ++i) {
        mrow[i] = -1e30f; lrow[i] = 0.f;
#pragma unroll
        for (int c = 0; c < 8; ++c) o[i][c] = 0.f;
    }

    const int jjmax = 2*qb + 1;
    for (int jj = 0; jj <= jjmax; ++jj) {
        const int kv0 = jj * 32;
        __syncthreads();   // prev PV done before restaging K/V (covers Q on iter 0)
#pragma unroll
        for (int i = 0; i < 4; ++i) {
            int f4 = i*256 + t;
            int r  = f4 >> 5, bd = f4 & 31;
            int sw = r*32 + (bd ^ (r & 7));
            Ks[sw] = *(const float4*)(Kp + headoff + (size_t)(kv0 + r)*D_HEAD + bd*4);
            Vs[sw] = *(const float4*)(Vp + headoff + (size_t)(kv0 + r)*D_HEAD + bd*4);
        }
        __syncthreads();

        // ---- scores: S[i][j] = Q[4ty+i] . K[16j+tx]  (scale pre-folded) ----
        float sc[4][2];
#pragma unroll
        for (int i = 0; i < 4; ++i) { sc[i][0] = 0.f; sc[i][1] = 0.f; }
        const int swk = tx & 7;
#pragma unroll 4
        for (int bd = 0; bd < 32; ++bd) {
            float4 kf0 = Ks[tx*32        + (bd ^ swk)];
            float4 kf1 = Ks[(16+tx)*32   + (bd ^ swk)];
#pragma unroll
            for (int i = 0; i < 4; ++i) {
                int r = 4*ty + i;
                float4 qf = Qs[r*32 + (bd ^ (r & 7))];
                sc[i][0] = fmaf(qf.w, kf0.w, fmaf(qf.z, kf0.z, fmaf(qf.y, kf0.y, fmaf(qf.x, kf0.x, sc[i][0]))));
                sc[i][1] = fmaf(qf.w, kf1.w, fmaf(qf.z, kf1.z, fmaf(qf.y, kf1.y, fmaf(qf.x, kf1.x, sc[i][1]))));
            }
        }

        // causal mask (only last two tiles can be partial)
        if (jj >= 2*qb) {
#pragma unroll
            for (int i = 0; i < 4; ++i) {
                int rg = q0 + 4*ty + i;
#pragma unroll
                for (int j = 0; j < 2; ++j) {
                    int cg = kv0 + j*16 + tx;
                    if (cg > rg) sc[i][j] = -1e30f;
                }
            }
        }

        // ---- online softmax (row spread over 16 lanes) ----
        float p[4][2];
#pragma unroll
        for (int i = 0; i < 4; ++i) {
            float mx = fmaxf(sc[i][0], sc[i][1]);
            mx = fmaxf(mx, __shfl_xor(mx, 1, 64));
            mx = fmaxf(mx, __shfl_xor(mx, 2, 64));
            mx = fmaxf(mx, __shfl_xor(mx, 4, 64));
            mx = fmaxf(mx, __shfl_xor(mx, 8, 64));
            float newm  = fmaxf(mrow[i], mx);
            float alpha = __expf(mrow[i] - newm);
            mrow[i] = newm;
            p[i][0] = __expf(sc[i][0] - newm);
            p[i][1] = __expf(sc[i][1] - newm);
            float rs = p[i][0] + p[i][1];
            rs += __shfl_xor(rs, 1, 64);
            rs += __shfl_xor(rs, 2, 64);
            rs += __shfl_xor(rs, 4, 64);
            rs += __shfl_xor(rs, 8, 64);
            lrow[i] = lrow[i]*alpha + rs;
#pragma unroll
            for (int c = 0; c < 8; ++c) o[i][c] *= alpha;
        }

        // ---- PV: O[r][*] += sum_k P[r][k] * V[k][*], P via shfl broadcast ----
        const int gbase = t & 48;
#pragma unroll
        for (int j = 0; j < 2; ++j) {
            for (int sl = 0; sl < 16; ++sl) {
                int k   = j*16 + sl;
                int src = gbase | sl;
                float pk0 = __shfl(p[0][j], src, 64);
                float pk1 = __shfl(p[1][j], src, 64);
                float pk2 = __shfl(p[2][j], src, 64);
                float pk3 = __shfl(p[3][j], src, 64);
                int sw = tx ^ (k & 7);
                float4 vlo = Vs[k*32 + sw];
                float4 vhi = Vs[k*32 + 16 + sw];
                o[0][0] = fmaf(pk0, vlo.x, o[0][0]); o[0][1] = fmaf(pk0, vlo.y, o[0][1]);
                o[0][2] = fmaf(pk0, vlo.z, o[0][2]); o[0][3] = fmaf(pk0, vlo.w, o[0][3]);
                o[0][4] = fmaf(pk0, vhi.x, o[0][4]); o[0][5] = fmaf(pk0, vhi.y, o[0][5]);
                o[0][6] = fmaf(pk0, vhi.z, o[0][6]); o[0][7] = fmaf(pk0, vhi.w, o[0][7]);
                o[1][0] = fmaf(pk1, vlo.x, o[1][0]); o[1][1] = fmaf(pk1, vlo.y, o[1][1]);
                o[1][2] = fmaf(pk1, vlo.z, o[1][2]); o[1][3] = fmaf(pk1, vlo.w, o[1][3]);
                o[1][4] = fmaf(pk1, vhi.x, o[1][4]); o[1][5] = fmaf(pk1, vhi.y, o[1][5]);
                o[1][6] = fmaf(pk1, vhi.z, o[1][6]); o[1][7] = fmaf(pk1, vhi.w, o[1][7]);
                o[2][0] = fmaf(pk2, vlo.x, o[2][0]); o[2][1] = fmaf(pk2, vlo.y, o[2][1]);
                o[2][2] = fmaf(pk2, vlo.z, o[2][2]); o[2][3] = fmaf(pk2, vlo.w, o[2][3]);
                o[2][4] = fmaf(pk2, vhi.x, o[2][4]); o[2][5] = fmaf(pk2, vhi.y, o[2][5]);
                o[2][6] = fmaf(pk2, vhi.z, o[2][6]); o[2][7] = fmaf(pk2, vhi.w, o[2][7]);
                o[3][0] = fmaf(pk3, vlo.x, o[3][0]); o[3][1] = fmaf(pk3, vlo.y, o[3][1]);
                o[3][2] = fmaf(pk3, vlo.z, o[3][2]); o[3][3] = fmaf(pk3, vlo.w, o[3][3]);
                o[3][4] = fmaf(pk3, vhi.x, o[3][4]); o[3][5] = fmaf(pk3, vhi.y, o[3][5]);
                o[3][6] = fmaf(pk3, vhi.z, o[3][6]); o[3][7] = fmaf(pk3, vhi.w, o[3][7]);
            }
        }
    }

    // ---- finalize & write (S,B,D_MODEL) layout for the out-proj GEMM ----
    const int bb = bh >> 4, h = bh & 15;
#pragma unroll
    for (int i = 0; i < 4; ++i) {
        float inv = 1.0f / lrow[i];
        int s  = q0 + 4*ty + i;
        size_t base = (size_t)(s*BATCH + bb) * D_MODEL + h*D_HEAD;
        float4 w0 = make_float4(o[i][0]*inv, o[i][1]*inv, o[i][2]*inv, o[i][3]*inv);
        float4 w1 = make_float4(o[i][4]*inv, o[i][5]*inv, o[i][6]*inv, o[i][7]*inv);
        *(float4*)(Op + base + tx*4)      = w0;
        *(float4*)(Op + base + 64 + tx*4) = w1;
    }
}

// ---------------------------------------------------------------------------
// Kernel 3: output projection. Same GEMM core, plain bias epilogue.
// ---------------------------------------------------------------------------
__global__ __launch_bounds__(256, 3) void out_proj_kernel(
    const float* __restrict__ A,      // (4096, 2048) attention output
    const float* __restrict__ W,      // (2048, 2048)
    const float* __restrict__ bias,   // (2048)
    float* __restrict__ Out)          // (4096, 2048)
{
    __shared__ float As[16][128];
    __shared__ float Bs[16][128];
    const int t  = threadIdx.x;
    const int tx = t & 15, ty = t >> 4;
    const int m0 = blockIdx.x * 128;
    const int n0 = blockIdx.y * 128;
    const int srow = t >> 1;
    const int sk   = (t & 1) * 8;

    const float* arow = A + (size_t)(m0 + srow) * D_MODEL + sk;
    const float* brow = W + (size_t)(n0 + srow) * D_MODEL + sk;

    float acc[8][8];
#pragma unroll
    for (int i = 0; i < 8; ++i)
#pragma unroll
        for (int j = 0; j < 8; ++j) acc[i][j] = 0.f;

    float4 a0 = *(const float4*)(arow);
    float4 a1 = *(const float4*)(arow + 4);
    float4 b0 = *(const float4*)(brow);
    float4 b1 = *(const float4*)(brow + 4);

    for (int k0 = 0; k0 < D_MODEL; k0 += 16) {
        __syncthreads();
        As[sk+0][srow] = a0.x; As[sk+1][srow] = a0.y; As[sk+2][srow] = a0.z; As[sk+3][srow] = a0.w;
        As[sk+4][srow] = a1.x; As[sk+5][srow] = a1.y; As[sk+6][srow] = a1.z; As[sk+7][srow] = a1.w;
        Bs[sk+0][srow] = b0.x; Bs[sk+1][srow] = b0.y; Bs[sk+2][srow] = b0.z; Bs[sk+3][srow] = b0.w;
        Bs[sk+4][srow] = b1.x; Bs[sk+5][srow] = b1.y; Bs[sk+6][srow] = b1.z; Bs[sk+7][srow] = b1.w;
        __syncthreads();
        if (k0 + 16 < D_MODEL) {
            a0 = *(const float4*)(arow + k0 + 16);
            a1 = *(const float4*)(arow + k0 + 20);
            b0 = *(const float4*)(brow + k0 + 16);
            b1 = *(const float4*)(brow + k0 + 20);
        }
#pragma unroll
        for (int kk = 0; kk < 16; ++kk) {
            float4 alo = *(const float4*)&As[kk][ty*4];
            float4 ahi = *(const float4*)&As[kk][64 + ty*4];
            float4 blo = *(const float4*)&Bs[kk][tx*4];
            float4 bhi = *(const float4*)&Bs[kk][64 + tx*4];
            float av[8] = {alo.x, alo.y, alo.z, alo.w, ahi.x, ahi.y, ahi.z, ahi.w};
            float bv[8] = {blo.x, blo.y, blo.z, blo.w, bhi.x, bhi.y, bhi.z, bhi.w};
#pragma unroll
            for (int i = 0; i < 8; ++i)
#pragma unroll
                for (int j = 0; j < 8; ++j)
                    acc[i][j] = fmaf(av[i], bv[j], acc[i][j]);
        }
    }

    float4 blo4 = *(const float4*)&bias[n0 + tx*4];
    float4 bhi4 = *(const float4*)&bias[n0 + 64 + tx*4];
#pragma unroll
    for (int i = 0; i < 8; ++i) {
        const int m = m0 + ((i < 4) ? (ty*4 + i) : (64 + ty*4 + (i-4)));
        float4 w0 = make_float4(acc[i][0] + blo4.x, acc[i][1] + blo4.y,
                                acc[i][2] + blo4.z, acc[i][3] + blo4.w);
        float4 w1 = make_float4(acc[i][4] + bhi4.x, acc[i][5] + bhi4.y,
                                acc[i][6] + bhi4.z, acc[i][7] + bhi4.w);
        *(float4*)(Out + (size_t)m * D_MODEL + n0 + tx*4)      = w0;
        *(float4*)(Out + (size_t)m * D_MODEL + n0 + 64 + tx*4) = w1;
    }
}

extern "C" void kernel_launch(void* const* d_in, const int* in_sizes, int n_in,
                              void* d_out, int out_size, void* d_ws, size_t ws_size,
                              hipStream_t stream) {
    const float* x      = (const float*)d_in[0];
    const float* freqs  = (const float*)d_in[1];
    const float* W_qkv  = (const float*)d_in[2];
    const float* b_qkv  = (const float*)d_in[3];
    const float* W_o    = (const float*)d_in[4];
    const float* b_o    = (const float*)d_in[5];
    float* out = (float*)d_out;

    // workspace: Q, K, V in (B,H,S,D) + attn out in (S*B, D_MODEL); 128 MiB total
    const size_t SZ = (size_t)M_ROWS * D_MODEL;  // 8388608 floats
    float* ws   = (float*)d_ws;
    float* Qp   = ws;
    float* Kp   = ws + SZ;
    float* Vp   = ws + 2*SZ;
    float* attn = ws + 3*SZ;

    qkv_rope_kernel<<<dim3(M_ROWS/128, QKV_N/128), 256, 0, stream>>>(
        x, W_qkv, b_qkv, freqs, Qp, Kp, Vp);
    attn_kernel<<<dim3(SEQ/64, BATCH*N_HEADS), 256, 0, stream>>>(Qp, Kp, Vp, attn);
    out_proj_kernel<<<dim3(M_ROWS/128, D_MODEL/128), 256, 0, stream>>>(
        attn, W_o, b_o, out);
}

// Round 4
// 1361.545 us; speedup vs baseline: 2.1718x; 2.1718x over previous
//
#include <hip/hip_runtime.h>

#define D_MODEL 2048
#define N_HEADS 16
#define D_HEAD 128
#define SEQ 2048
#define BATCH 2
#define M_ROWS (SEQ*BATCH)     // 4096
#define QKV_N  (3*D_MODEL)     // 6144
#define ATTN_SCALE 0.08838834764831845f

typedef __attribute__((ext_vector_type(8))) short short8v;   // 8 bf16 (4 VGPR)
typedef __attribute__((ext_vector_type(4))) float float4v;   // 4 f32 acc
typedef unsigned short u16;
typedef unsigned int   u32;

// bf16 round-to-nearest-even split helpers (no __hip_bfloat16 API dependence)
__device__ __forceinline__ u16 f32_bf16_rne(float f) {
    u32 u = __float_as_uint(f);
    return (u16)((u + 0x7FFFu + ((u >> 16) & 1u)) >> 16);
}
__device__ __forceinline__ float bf16_f32(u16 h) {
    return __uint_as_float(((u32)h) << 16);
}

// Stage one 4xfloat4 strip (16 f32) into hi/lo bf16 LDS, k-major [g][row][j].
// k_local = half*16 + 4q + comp ; g = half*2 + (q>>1) ; j = (q&1)*4 + comp
#define STAGE_SPLIT(vv, sH, sL)                                              \
    {                                                                        \
        _Pragma("unroll")                                                    \
        for (int q = 0; q < 4; ++q) {                                        \
            float4 v = vv[q];                                                \
            int off = ((half*2 + (q>>1))*128 + row)*8 + (q&1)*4;             \
            u16 h0 = f32_bf16_rne(v.x), h1 = f32_bf16_rne(v.y),              \
                h2 = f32_bf16_rne(v.z), h3 = f32_bf16_rne(v.w);              \
            ushort4 hv = make_ushort4(h0, h1, h2, h3);                       \
            ushort4 lv = make_ushort4(f32_bf16_rne(v.x - bf16_f32(h0)),      \
                                      f32_bf16_rne(v.y - bf16_f32(h1)),      \
                                      f32_bf16_rne(v.z - bf16_f32(h2)),      \
                                      f32_bf16_rne(v.w - bf16_f32(h3)));     \
            *(ushort4*)&sH[off] = hv;                                        \
            *(ushort4*)&sL[off] = lv;                                        \
        }                                                                    \
    }

// ---------------------------------------------------------------------------
// bf16x3 MFMA GEMM core (both projection kernels):
// C[m][n] = sum_k A[m][k] * B[n][k], M-tile 128 x N-tile 128, BK=32,
// 4 waves, each wave -> 64x64 (4x4 fragments of 16x16x32 MFMA).
// x3 split: C ≈ Ah·Bh + Ah·Bl + Al·Bh  (~17-bit mantissa, fp32-class).
// LDS k-major [g][row][j] so frag ds_read_b128 is contiguous per lane.
// D layout (m89-verified): a-dim row = (lane>>4)*4 + reg, b-dim col = lane&15.
// ---------------------------------------------------------------------------
#define GEMM_PROLOGUE()                                                      \
    __shared__ u16 sAh[4*128*8], sAl[4*128*8], sBh[4*128*8], sBl[4*128*8];   \
    const int t = threadIdx.x;                                               \
    const int m0 = blockIdx.x * 128, n0 = blockIdx.y * 128;                  \
    const int row = t >> 1, half = t & 1;                                    \
    const int lane = t & 63, wave = t >> 6;                                  \
    const int wm = wave >> 1, wn = wave & 1;                                 \
    const int l16 = lane & 15, lg = lane >> 4;                               \
    float4v acc[4][4];                                                       \
    _Pragma("unroll")                                                        \
    for (int i = 0; i < 4; ++i)                                              \
        _Pragma("unroll")                                                    \
        for (int j = 0; j < 4; ++j)                                          \
            _Pragma("unroll")                                                 \
            for (int r = 0; r < 4; ++r) acc[i][j][r] = 0.f;

#define GEMM_MAINLOOP(Aptr, Bptr)                                            \
    const float* Arow = (Aptr) + (size_t)(m0 + row) * D_MODEL + half*16;     \
    const float* Brow = (Bptr) + (size_t)(n0 + row) * D_MODEL + half*16;     \
    float4 pa[4], pb[4];                                                     \
    _Pragma("unroll")                                                        \
    for (int q = 0; q < 4; ++q) {                                            \
        pa[q] = ((const float4*)Arow)[q];                                    \
        pb[q] = ((const float4*)Brow)[q];                                    \
    }                                                                        \
    for (int kt = 0; kt < D_MODEL/32; ++kt) {                                \
        if (kt) __syncthreads();                                             \
        STAGE_SPLIT(pa, sAh, sAl);                                           \
        STAGE_SPLIT(pb, sBh, sBl);                                           \
        if (kt < D_MODEL/32 - 1) {                                           \
            Arow += 32; Brow += 32;                                          \
            _Pragma("unroll")                                                \
            for (int q = 0; q < 4; ++q) {                                    \
                pa[q] = ((const float4*)Arow)[q];                            \
                pb[q] = ((const float4*)Brow)[q];                            \
            }                                                                \
        }                                                                    \
        __syncthreads();                                                     \
        const int abase = lg*128 + wm*64 + l16;                              \
        const int bbase = lg*128 + wn*64 + l16;                              \
        short8v bh[4], bl[4];                                                \
        _Pragma("unroll")                                                    \
        for (int fn = 0; fn < 4; ++fn) {                                     \
            bh[fn] = ((const short8v*)sBh)[bbase + fn*16];                   \
            bl[fn] = ((const short8v*)sBl)[bbase + fn*16];                   \
        }                                                                    \
        _Pragma("unroll")                                                    \
        for (int fm = 0; fm < 4; ++fm) {                                     \
            short8v ah = ((const short8v*)sAh)[abase + fm*16];               \
            short8v al = ((const short8v*)sAl)[abase + fm*16];               \
            _Pragma("unroll")                                                \
            for (int fn = 0; fn < 4; ++fn) {                                 \
                acc[fm][fn] = __builtin_amdgcn_mfma_f32_16x16x32_bf16(       \
                    ah, bh[fn], acc[fm][fn], 0, 0, 0);                       \
                acc[fm][fn] = __builtin_amdgcn_mfma_f32_16x16x32_bf16(       \
                    ah, bl[fn], acc[fm][fn], 0, 0, 0);                       \
                acc[fm][fn] = __builtin_amdgcn_mfma_f32_16x16x32_bf16(       \
                    al, bh[fn], acc[fm][fn], 0, 0, 0);                       \
            }                                                                \
        }                                                                    \
    }

// Kernel 1: QKV projection (bf16x3 MFMA) + bias + RoPE + scatter (B,H,S,D)
__global__ __launch_bounds__(256, 2) void qkv_rope_mfma(
    const float* __restrict__ X,      // (4096, 2048) rows = s*B+b
    const float* __restrict__ W,      // (6144, 2048)
    const float* __restrict__ bias,   // (6144)
    const float* __restrict__ freqs,  // (2048, 64)
    float* __restrict__ Qp, float* __restrict__ Kp, float* __restrict__ Vp)
{
    GEMM_PROLOGUE();
    GEMM_MAINLOOP(X, W);

    // Epilogue: bias + RoPE (pair partner via shfl_xor 1) + scatter.
    // Block's 128 n-columns lie in exactly one of {Q,K,V} sections.
    const int sec = n0 >> 11;
    float* __restrict__ base = (sec == 0) ? Qp : ((sec == 1) ? Kp : Vp);
#pragma unroll
    for (int fn = 0; fn < 4; ++fn) {
        const int n = n0 + wn*64 + fn*16 + l16;
        const float bn = bias[n];
        const int d = n & 127, hd = (n >> 7) & 15;
#pragma unroll
        for (int fm = 0; fm < 4; ++fm) {
#pragma unroll
            for (int r = 0; r < 4; ++r) {
                const int m = m0 + wm*64 + fm*16 + lg*4 + r;
                const int s = m >> 1, bb = m & 1;
                float v = acc[fm][fn][r] + bn;
                float outv;
                if (sec == 2) {
                    outv = v;
                } else {
                    float partner = __shfl_xor(v, 1, 64);
                    float fr = freqs[(size_t)s * 64 + (d >> 1)];
                    float sn, cs;
                    sincosf(fr, &sn, &cs);
                    outv = (n & 1) ? (partner*sn + v*cs) : (v*cs - partner*sn);
                    if (sec == 0) outv *= ATTN_SCALE;
                }
                base[(((size_t)(bb*N_HEADS + hd) * SEQ) + s) * D_HEAD + d] = outv;
            }
        }
    }
}

// Kernel 3: output projection (bf16x3 MFMA) + bias
__global__ __launch_bounds__(256, 2) void out_proj_mfma(
    const float* __restrict__ A,      // (4096, 2048) attention output
    const float* __restrict__ W,      // (2048, 2048)
    const float* __restrict__ bias,   // (2048)
    float* __restrict__ Out)          // (4096, 2048)
{
    GEMM_PROLOGUE();
    GEMM_MAINLOOP(A, W);
#pragma unroll
    for (int fn = 0; fn < 4; ++fn) {
        const int n = n0 + wn*64 + fn*16 + l16;
        const float bn = bias[n];
#pragma unroll
        for (int fm = 0; fm < 4; ++fm) {
#pragma unroll
            for (int r = 0; r < 4; ++r) {
                const int m = m0 + wm*64 + fm*16 + lg*4 + r;
                Out[(size_t)m * D_MODEL + n] = acc[fm][fn][r] + bn;
            }
        }
    }
}

// ---------------------------------------------------------------------------
// Kernel 2: causal flash attention, fp32 (math unchanged from validated
// baseline). NEW: q-tile pairing (i, 31-i) -> every block does a constant
// 68 KV-tile iterations; grid 16x32 = 512 blocks = exactly 2 resident
// blocks/CU (64 KiB LDS) -> no load-imbalance tail.
// ---------------------------------------------------------------------------
__global__ __launch_bounds__(256, 2) void attn_kernel(
    const float* __restrict__ Qp, const float* __restrict__ Kp,
    const float* __restrict__ Vp, float* __restrict__ Op /* (4096,2048) */)
{
    __shared__ float4 smem[4096];          // 64 KiB
    float4* Qs = smem;                     // 64*32
    float4* Ks = smem + 2048;              // 32*32
    float4* Vs = smem + 3072;              // 32*32

    const int t  = threadIdx.x;
    const int tx = t & 15, ty = t >> 4;
    const int pairid = blockIdx.x;         // 0..15
    const int bh = blockIdx.y;
    const size_t headoff = (size_t)bh * SEQ * D_HEAD;

    for (int pass = 0; pass < 2; ++pass) {
        const int qb = pass ? (31 - pairid) : pairid;
        const int q0 = qb * 64;
        __syncthreads();   // protect Qs against previous pass still reading

        // stage Q tile (swizzled)
#pragma unroll
        for (int i = 0; i < 8; ++i) {
            int f4 = i*256 + t;
            int r  = f4 >> 5, bd = f4 & 31;
            float4 v = *(const float4*)(Qp + headoff + (size_t)(q0 + r)*D_HEAD + bd*4);
            Qs[r*32 + (bd ^ (r & 7))] = v;
        }

        float o[4][8];
        float mrow[4], lrow[4];
#pragma unroll
        for (int i = 0; i < 4; ++i) {
            mrow[i] = -1e30f; lrow[i] = 0.f;
#pragma unroll
            for (int c = 0; c < 8; ++c) o[i][c] = 0.f;
        }

        const int jjmax = 2*qb + 1;
        for (int jj = 0; jj <= jjmax; ++jj) {
            const int kv0 = jj * 32;
            __syncthreads();   // prev PV done before restaging K/V (covers Q too)
#pragma unroll
            for (int i = 0; i < 4; ++i) {
                int f4 = i*256 + t;
                int r  = f4 >> 5, bd = f4 & 31;
                int sw = r*32 + (bd ^ (r & 7));
                Ks[sw] = *(const float4*)(Kp + headoff + (size_t)(kv0 + r)*D_HEAD + bd*4);
                Vs[sw] = *(const float4*)(Vp + headoff + (size_t)(kv0 + r)*D_HEAD + bd*4);
            }
            __syncthreads();

            // ---- scores: S[i][j] = Q[4ty+i] . K[16j+tx] (scale pre-folded) ----
            float sc[4][2];
#pragma unroll
            for (int i = 0; i < 4; ++i) { sc[i][0] = 0.f; sc[i][1] = 0.f; }
            const int swk = tx & 7;
#pragma unroll 4
            for (int bd = 0; bd < 32; ++bd) {
                float4 kf0 = Ks[tx*32      + (bd ^ swk)];
                float4 kf1 = Ks[(16+tx)*32 + (bd ^ swk)];
#pragma unroll
                for (int i = 0; i < 4; ++i) {
                    int r = 4*ty + i;
                    float4 qf = Qs[r*32 + (bd ^ (r & 7))];
                    sc[i][0] = fmaf(qf.w, kf0.w, fmaf(qf.z, kf0.z, fmaf(qf.y, kf0.y, fmaf(qf.x, kf0.x, sc[i][0]))));
                    sc[i][1] = fmaf(qf.w, kf1.w, fmaf(qf.z, kf1.z, fmaf(qf.y, kf1.y, fmaf(qf.x, kf1.x, sc[i][1]))));
                }
            }

            // causal mask (only last two tiles can be partial)
            if (jj >= 2*qb) {
#pragma unroll
                for (int i = 0; i < 4; ++i) {
                    int rg = q0 + 4*ty + i;
#pragma unroll
                    for (int j = 0; j < 2; ++j) {
                        int cg = kv0 + j*16 + tx;
                        if (cg > rg) sc[i][j] = -1e30f;
                    }
                }
            }

            // ---- online softmax (row spread over 16 lanes) ----
            float p[4][2];
#pragma unroll
            for (int i = 0; i < 4; ++i) {
                float mx = fmaxf(sc[i][0], sc[i][1]);
                mx = fmaxf(mx, __shfl_xor(mx, 1, 64));
                mx = fmaxf(mx, __shfl_xor(mx, 2, 64));
                mx = fmaxf(mx, __shfl_xor(mx, 4, 64));
                mx = fmaxf(mx, __shfl_xor(mx, 8, 64));
                float newm  = fmaxf(mrow[i], mx);
                float alpha = __expf(mrow[i] - newm);
                mrow[i] = newm;
                p[i][0] = __expf(sc[i][0] - newm);
                p[i][1] = __expf(sc[i][1] - newm);
                float rs = p[i][0] + p[i][1];
                rs += __shfl_xor(rs, 1, 64);
                rs += __shfl_xor(rs, 2, 64);
                rs += __shfl_xor(rs, 4, 64);
                rs += __shfl_xor(rs, 8, 64);
                lrow[i] = lrow[i]*alpha + rs;
#pragma unroll
                for (int c = 0; c < 8; ++c) o[i][c] *= alpha;
            }

            // ---- PV: O[r][*] += sum_k P[r][k]*V[k][*], P via shfl broadcast ----
            const int gbase = t & 48;
#pragma unroll
            for (int j = 0; j < 2; ++j) {
                for (int sl = 0; sl < 16; ++sl) {
                    int k   = j*16 + sl;
                    int src = gbase | sl;
                    float pk0 = __shfl(p[0][j], src, 64);
                    float pk1 = __shfl(p[1][j], src, 64);
                    float pk2 = __shfl(p[2][j], src, 64);
                    float pk3 = __shfl(p[3][j], src, 64);
                    int sw = tx ^ (k & 7);
                    float4 vlo = Vs[k*32 + sw];
                    float4 vhi = Vs[k*32 + 16 + sw];
                    o[0][0] = fmaf(pk0, vlo.x, o[0][0]); o[0][1] = fmaf(pk0, vlo.y, o[0][1]);
                    o[0][2] = fmaf(pk0, vlo.z, o[0][2]); o[0][3] = fmaf(pk0, vlo.w, o[0][3]);
                    o[0][4] = fmaf(pk0, vhi.x, o[0][4]); o[0][5] = fmaf(pk0, vhi.y, o[0][5]);
                    o[0][6] = fmaf(pk0, vhi.z, o[0][6]); o[0][7] = fmaf(pk0, vhi.w, o[0][7]);
                    o[1][0] = fmaf(pk1, vlo.x, o[1][0]); o[1][1] = fmaf(pk1, vlo.y, o[1][1]);
                    o[1][2] = fmaf(pk1, vlo.z, o[1][2]); o[1][3] = fmaf(pk1, vlo.w, o[1][3]);
                    o[1][4] = fmaf(pk1, vhi.x, o[1][4]); o[1][5] = fmaf(pk1, vhi.y, o[1][5]);
                    o[1][6] = fmaf(pk1, vhi.z, o[1][6]); o[1][7] = fmaf(pk1, vhi.w, o[1][7]);
                    o[2][0] = fmaf(pk2, vlo.x, o[2][0]); o[2][1] = fmaf(pk2, vlo.y, o[2][1]);
                    o[2][2] = fmaf(pk2, vlo.z, o[2][2]); o[2][3] = fmaf(pk2, vlo.w, o[2][3]);
                    o[2][4] = fmaf(pk2, vhi.x, o[2][4]); o[2][5] = fmaf(pk2, vhi.y, o[2][5]);
                    o[2][6] = fmaf(pk2, vhi.z, o[2][6]); o[2][7] = fmaf(pk2, vhi.w, o[2][7]);
                    o[3][0] = fmaf(pk3, vlo.x, o[3][0]); o[3][1] = fmaf(pk3, vlo.y, o[3][1]);
                    o[3][2] = fmaf(pk3, vlo.z, o[3][2]); o[3][3] = fmaf(pk3, vlo.w, o[3][3]);
                    o[3][4] = fmaf(pk3, vhi.x, o[3][4]); o[3][5] = fmaf(pk3, vhi.y, o[3][5]);
                    o[3][6] = fmaf(pk3, vhi.z, o[3][6]); o[3][7] = fmaf(pk3, vhi.w, o[3][7]);
                }
            }
        }

        // ---- finalize & write (S,B,D_MODEL) layout for the out-proj GEMM ----
        const int bb = bh >> 4, h = bh & 15;
#pragma unroll
        for (int i = 0; i < 4; ++i) {
            float inv = 1.0f / lrow[i];
            int s  = q0 + 4*ty + i;
            size_t base = (size_t)(s*BATCH + bb) * D_MODEL + h*D_HEAD;
            float4 w0 = make_float4(o[i][0]*inv, o[i][1]*inv, o[i][2]*inv, o[i][3]*inv);
            float4 w1 = make_float4(o[i][4]*inv, o[i][5]*inv, o[i][6]*inv, o[i][7]*inv);
            *(float4*)(Op + base + tx*4)      = w0;
            *(float4*)(Op + base + 64 + tx*4) = w1;
        }
    }
}

extern "C" void kernel_launch(void* const* d_in, const int* in_sizes, int n_in,
                              void* d_out, int out_size, void* d_ws, size_t ws_size,
                              hipStream_t stream) {
    const float* x      = (const float*)d_in[0];
    const float* freqs  = (const float*)d_in[1];
    const float* W_qkv  = (const float*)d_in[2];
    const float* b_qkv  = (const float*)d_in[3];
    const float* W_o    = (const float*)d_in[4];
    const float* b_o    = (const float*)d_in[5];
    float* out = (float*)d_out;

    // workspace: Q, K, V in (B,H,S,D) + attn out in (S*B, D_MODEL); 128 MiB
    const size_t SZ = (size_t)M_ROWS * D_MODEL;  // 8388608 floats
    float* ws   = (float*)d_ws;
    float* Qp   = ws;
    float* Kp   = ws + SZ;
    float* Vp   = ws + 2*SZ;
    float* attn = ws + 3*SZ;

    qkv_rope_mfma<<<dim3(M_ROWS/128, QKV_N/128), 256, 0, stream>>>(
        x, W_qkv, b_qkv, freqs, Qp, Kp, Vp);
    attn_kernel<<<dim3(16, BATCH*N_HEADS), 256, 0, stream>>>(Qp, Kp, Vp, attn);
    out_proj_mfma<<<dim3(M_ROWS/128, D_MODEL/128), 256, 0, stream>>>(
        attn, W_o, b_o, out);
}

// Round 5
// 856.663 us; speedup vs baseline: 3.4518x; 1.5894x over previous
//
#include <hip/hip_runtime.h>

#define D_MODEL 2048
#define N_HEADS 16
#define D_HEAD 128
#define SEQ 2048
#define BATCH 2
#define M_ROWS (SEQ*BATCH)     // 4096
#define QKV_N  (3*D_MODEL)     // 6144
#define ATTN_SCALE 0.08838834764831845f

typedef __attribute__((ext_vector_type(8))) short short8v;   // 8 bf16 (4 VGPR)
typedef __attribute__((ext_vector_type(4))) float float4v;   // 4 f32 acc
typedef __attribute__((ext_vector_type(2))) unsigned int uint2v;
typedef __attribute__((ext_vector_type(4))) unsigned int uint4v;
typedef unsigned short u16;
typedef unsigned int   u32;

__device__ __forceinline__ u16 f32_bf16_rne(float f) {
    u32 u = __float_as_uint(f);
    return (u16)((u + 0x7FFFu + ((u >> 16) & 1u)) >> 16);
}
__device__ __forceinline__ float bf16_f32(u16 h) {
    return __uint_as_float(((u32)h) << 16);
}

// ---------------------------------------------------------------------------
// bf16x3 MFMA GEMM core (unchanged from validated R4 kernel)
// ---------------------------------------------------------------------------
#define STAGE_SPLIT(vv, sH, sL)                                              \
    {                                                                        \
        _Pragma("unroll")                                                    \
        for (int q = 0; q < 4; ++q) {                                        \
            float4 v = vv[q];                                                \
            int off = ((half*2 + (q>>1))*128 + row)*8 + (q&1)*4;             \
            u16 h0 = f32_bf16_rne(v.x), h1 = f32_bf16_rne(v.y),              \
                h2 = f32_bf16_rne(v.z), h3 = f32_bf16_rne(v.w);              \
            ushort4 hv = make_ushort4(h0, h1, h2, h3);                       \
            ushort4 lv = make_ushort4(f32_bf16_rne(v.x - bf16_f32(h0)),      \
                                      f32_bf16_rne(v.y - bf16_f32(h1)),      \
                                      f32_bf16_rne(v.z - bf16_f32(h2)),      \
                                      f32_bf16_rne(v.w - bf16_f32(h3)));     \
            *(ushort4*)&sH[off] = hv;                                        \
            *(ushort4*)&sL[off] = lv;                                        \
        }                                                                    \
    }

#define GEMM_PROLOGUE()                                                      \
    __shared__ u16 sAh[4*128*8], sAl[4*128*8], sBh[4*128*8], sBl[4*128*8];   \
    const int t = threadIdx.x;                                               \
    const int m0 = blockIdx.x * 128, n0 = blockIdx.y * 128;                  \
    const int row = t >> 1, half = t & 1;                                    \
    const int lane = t & 63, wave = t >> 6;                                  \
    const int wm = wave >> 1, wn = wave & 1;                                 \
    const int l16 = lane & 15, lg = lane >> 4;                               \
    float4v acc[4][4];                                                       \
    _Pragma("unroll")                                                        \
    for (int i = 0; i < 4; ++i)                                              \
        _Pragma("unroll")                                                    \
        for (int j = 0; j < 4; ++j)                                          \
            _Pragma("unroll")                                                 \
            for (int r = 0; r < 4; ++r) acc[i][j][r] = 0.f;

#define GEMM_MAINLOOP(Aptr, Bptr)                                            \
    const float* Arow = (Aptr) + (size_t)(m0 + row) * D_MODEL + half*16;     \
    const float* Brow = (Bptr) + (size_t)(n0 + row) * D_MODEL + half*16;     \
    float4 pa[4], pb[4];                                                     \
    _Pragma("unroll")                                                        \
    for (int q = 0; q < 4; ++q) {                                            \
        pa[q] = ((const float4*)Arow)[q];                                    \
        pb[q] = ((const float4*)Brow)[q];                                    \
    }                                                                        \
    for (int kt = 0; kt < D_MODEL/32; ++kt) {                                \
        if (kt) __syncthreads();                                             \
        STAGE_SPLIT(pa, sAh, sAl);                                           \
        STAGE_SPLIT(pb, sBh, sBl);                                           \
        if (kt < D_MODEL/32 - 1) {                                           \
            Arow += 32; Brow += 32;                                          \
            _Pragma("unroll")                                                \
            for (int q = 0; q < 4; ++q) {                                    \
                pa[q] = ((const float4*)Arow)[q];                            \
                pb[q] = ((const float4*)Brow)[q];                            \
            }                                                                \
        }                                                                    \
        __syncthreads();                                                     \
        const int abase = lg*128 + wm*64 + l16;                              \
        const int bbase = lg*128 + wn*64 + l16;                              \
        short8v bh[4], bl[4];                                                \
        _Pragma("unroll")                                                    \
        for (int fn = 0; fn < 4; ++fn) {                                     \
            bh[fn] = ((const short8v*)sBh)[bbase + fn*16];                   \
            bl[fn] = ((const short8v*)sBl)[bbase + fn*16];                   \
        }                                                                    \
        _Pragma("unroll")                                                    \
        for (int fm = 0; fm < 4; ++fm) {                                     \
            short8v ah = ((const short8v*)sAh)[abase + fm*16];               \
            short8v al = ((const short8v*)sAl)[abase + fm*16];               \
            _Pragma("unroll")                                                \
            for (int fn = 0; fn < 4; ++fn) {                                 \
                acc[fm][fn] = __builtin_amdgcn_mfma_f32_16x16x32_bf16(       \
                    ah, bh[fn], acc[fm][fn], 0, 0, 0);                       \
                acc[fm][fn] = __builtin_amdgcn_mfma_f32_16x16x32_bf16(       \
                    ah, bl[fn], acc[fm][fn], 0, 0, 0);                       \
                acc[fm][fn] = __builtin_amdgcn_mfma_f32_16x16x32_bf16(       \
                    al, bh[fn], acc[fm][fn], 0, 0, 0);                       \
            }                                                                \
        }                                                                    \
    }

// Kernel 1: QKV projection + bias + RoPE; writes Q/K/V as bf16 hi/lo planes
__global__ __launch_bounds__(256, 2) void qkv_rope_mfma(
    const float* __restrict__ X, const float* __restrict__ W,
    const float* __restrict__ bias, const float* __restrict__ freqs,
    u16* __restrict__ Qh, u16* __restrict__ Ql,
    u16* __restrict__ Kh, u16* __restrict__ Kl,
    u16* __restrict__ Vh, u16* __restrict__ Vl)
{
    GEMM_PROLOGUE();
    GEMM_MAINLOOP(X, W);

    const int sec = n0 >> 11;
    u16* __restrict__ hb = (sec == 0) ? Qh : ((sec == 1) ? Kh : Vh);
    u16* __restrict__ lb = (sec == 0) ? Ql : ((sec == 1) ? Kl : Vl);
#pragma unroll
    for (int fn = 0; fn < 4; ++fn) {
        const int n = n0 + wn*64 + fn*16 + l16;
        const float bn = bias[n];
        const int d = n & 127, hd = (n >> 7) & 15;
#pragma unroll
        for (int fm = 0; fm < 4; ++fm) {
#pragma unroll
            for (int r = 0; r < 4; ++r) {
                const int mrow = m0 + wm*64 + fm*16 + lg*4 + r;
                const int s = mrow >> 1, bb = mrow & 1;
                float v = acc[fm][fn][r] + bn;
                float outv;
                if (sec == 2) {
                    outv = v;
                } else {
                    float partner = __shfl_xor(v, 1, 64);
                    float fr = freqs[(size_t)s * 64 + (d >> 1)];
                    float sn, cs;
                    sincosf(fr, &sn, &cs);
                    outv = (n & 1) ? (partner*sn + v*cs) : (v*cs - partner*sn);
                    if (sec == 0) outv *= ATTN_SCALE;
                }
                size_t off = (((size_t)(bb*N_HEADS + hd) * SEQ) + s) * D_HEAD + d;
                u16 h = f32_bf16_rne(outv);
                hb[off] = h;
                lb[off] = f32_bf16_rne(outv - bf16_f32(h));
            }
        }
    }
}

// Kernel 3: output projection (unchanged)
__global__ __launch_bounds__(256, 2) void out_proj_mfma(
    const float* __restrict__ A, const float* __restrict__ W,
    const float* __restrict__ bias, float* __restrict__ Out)
{
    GEMM_PROLOGUE();
    GEMM_MAINLOOP(A, W);
#pragma unroll
    for (int fn = 0; fn < 4; ++fn) {
        const int n = n0 + wn*64 + fn*16 + l16;
        const float bn = bias[n];
#pragma unroll
        for (int fm = 0; fm < 4; ++fm) {
#pragma unroll
            for (int r = 0; r < 4; ++r) {
                const int mrow = m0 + wm*64 + fm*16 + lg*4 + r;
                Out[(size_t)mrow * D_MODEL + n] = acc[fm][fn][r] + bn;
            }
        }
    }
}

// ---------------------------------------------------------------------------
// Kernel 2: causal flash attention, bf16x3 MFMA.
// 4 waves, Q-tile 64 (wave w: rows w*16..+15), KV-tile 32, q-tile pairing.
// Swapped scores S^T = mfma(K, Q): lane owns q = lane&15; softmax via 2 shfl.
// PV: O^T = mfma(V^T, P) with V^T delivered by ds_read_b64_tr_b16.
// LDS 64 KiB: Qh/Ql [g16][q64][8], Kh/Kl [kv][g^(kv&7)][8], Vh/Vl 4x16 regions.
// ---------------------------------------------------------------------------
#define QH_O 0
#define QL_O 8192
#define KH_O 16384
#define KL_O 20480
#define VH_O 24576
#define VL_O 28672

#define PV_DB(DB)                                                            \
    {                                                                        \
        uint2v th0, th1, tl0, tl1;                                           \
        u32 aH = vbH + DB*1024, aL = vbL + DB*1024;                          \
        asm volatile("ds_read_b64_tr_b16 %0, %4\n\t"                         \
                     "ds_read_b64_tr_b16 %1, %4 offset:128\n\t"              \
                     "ds_read_b64_tr_b16 %2, %5\n\t"                         \
                     "ds_read_b64_tr_b16 %3, %5 offset:128\n\t"              \
                     "s_waitcnt lgkmcnt(0)"                                  \
                     : "=v"(th0), "=v"(th1), "=v"(tl0), "=v"(tl1)            \
                     : "v"(aH), "v"(aL));                                    \
        __builtin_amdgcn_sched_barrier(0);                                   \
        uint4v uh; uh.x = th0.x; uh.y = th0.y; uh.z = th1.x; uh.w = th1.y;   \
        uint4v ul; ul.x = tl0.x; ul.y = tl0.y; ul.z = tl1.x; ul.w = tl1.y;   \
        short8v vfh = __builtin_bit_cast(short8v, uh);                       \
        short8v vfl = __builtin_bit_cast(short8v, ul);                       \
        o[DB] = __builtin_amdgcn_mfma_f32_16x16x32_bf16(vfh, pfh, o[DB], 0,0,0); \
        o[DB] = __builtin_amdgcn_mfma_f32_16x16x32_bf16(vfh, pfl, o[DB], 0,0,0); \
        o[DB] = __builtin_amdgcn_mfma_f32_16x16x32_bf16(vfl, pfh, o[DB], 0,0,0); \
    }

__global__ __launch_bounds__(256, 2) void attn_mfma(
    const u16* __restrict__ Qh_g, const u16* __restrict__ Ql_g,
    const u16* __restrict__ Kh_g, const u16* __restrict__ Kl_g,
    const u16* __restrict__ Vh_g, const u16* __restrict__ Vl_g,
    float* __restrict__ Op)
{
    __shared__ __align__(16) u16 lds[32768];   // 64 KiB

    const int t = threadIdx.x;
    const int lane = t & 63, wave = t >> 6;
    const int l16 = lane & 15, lg = lane >> 4;

    // XCD-aware mapping: XCD x owns heads 4x..4x+3 (KV L2 locality)
    const int bid = blockIdx.x;
    const int bh = (bid & 7) * 4 + ((bid >> 3) >> 4);
    const int pairid = (bid >> 3) & 15;
    const size_t ho = (size_t)bh * SEQ * D_HEAD;

    const int skv = t >> 3;        // staging K/V row 0..31
    const int sdb = t & 7;         // staging d-block

    const u32 ldsb = (u32)(uintptr_t)lds;
    const u32 vbH = ldsb + VH_O*2 + lg*256 + l16*8;
    const u32 vbL = ldsb + VL_O*2 + lg*256 + l16*8;

    for (int pass = 0; pass < 2; ++pass) {
        const int qb = pass ? (31 - pairid) : pairid;
        const int q0 = qb * 64;
        __syncthreads();
        // ---- stage Q tile (hi+lo), k-major [g][q][8] ----
#pragma unroll
        for (int i = 0; i < 2; ++i) {
            int task = i*256 + t;
            int qr = task >> 3, db = task & 7;
            size_t gsrc = ho + (size_t)(q0 + qr)*128 + db*16;
            uint4 h0 = *(const uint4*)(Qh_g + gsrc);
            uint4 h1 = *(const uint4*)(Qh_g + gsrc + 8);
            uint4 L0 = *(const uint4*)(Ql_g + gsrc);
            uint4 L1 = *(const uint4*)(Ql_g + gsrc + 8);
            *(uint4*)&lds[QH_O + ((db*2  )*64 + qr)*8] = h0;
            *(uint4*)&lds[QH_O + ((db*2+1)*64 + qr)*8] = h1;
            *(uint4*)&lds[QL_O + ((db*2  )*64 + qr)*8] = L0;
            *(uint4*)&lds[QL_O + ((db*2+1)*64 + qr)*8] = L1;
        }
        __syncthreads();
        // ---- Q fragments to registers (persist across KV loop) ----
        short8v qfh[4], qfl[4];
#pragma unroll
        for (int c = 0; c < 4; ++c) {
            int g = c*4 + lg;
            qfh[c] = *(const short8v*)&lds[QH_O + (g*64 + wave*16 + l16)*8];
            qfl[c] = *(const short8v*)&lds[QL_O + (g*64 + wave*16 + l16)*8];
        }

        float4v o[8];
#pragma unroll
        for (int db = 0; db < 8; ++db)
#pragma unroll
            for (int r = 0; r < 4; ++r) o[db][r] = 0.f;
        float m_s = -1e30f, l_s = 0.f;

        const int jjmax = 2*qb + 1;
        for (int jj = 0; jj <= jjmax; ++jj) {
            const int kv0 = jj * 32;
            __syncthreads();
            // ---- stage K (swizzled k-major) and V (tr-read regions) ----
            {
                size_t gk = ho + (size_t)(kv0 + skv)*128 + sdb*16;
                uint4 kh0 = *(const uint4*)(Kh_g + gk);
                uint4 kh1 = *(const uint4*)(Kh_g + gk + 8);
                uint4 kl0 = *(const uint4*)(Kl_g + gk);
                uint4 kl1 = *(const uint4*)(Kl_g + gk + 8);
                uint4 vh0 = *(const uint4*)(Vh_g + gk);
                uint4 vh1 = *(const uint4*)(Vh_g + gk + 8);
                uint4 vl0 = *(const uint4*)(Vl_g + gk);
                uint4 vl1 = *(const uint4*)(Vl_g + gk + 8);
                const int k7 = skv & 7;
                const int g0 = sdb*2, g1 = sdb*2 + 1;
                *(uint4*)&lds[KH_O + skv*128 + ((g0^k7)<<3)] = kh0;
                *(uint4*)&lds[KH_O + skv*128 + ((g1^k7)<<3)] = kh1;
                *(uint4*)&lds[KL_O + skv*128 + ((g0^k7)<<3)] = kl0;
                *(uint4*)&lds[KL_O + skv*128 + ((g1^k7)<<3)] = kl1;
                const int vreg = (sdb*8 + (skv>>2))*64 + (skv&3)*16;
                *(uint4*)&lds[VH_O + vreg]     = vh0;
                *(uint4*)&lds[VH_O + vreg + 8] = vh1;
                *(uint4*)&lds[VL_O + vreg]     = vl0;
                *(uint4*)&lds[VL_O + vreg + 8] = vl1;
            }
            __syncthreads();

            // ---- scores S^T: rows kv = lg*4+r (+16), cols q = l16 ----
            float4v s0 = {0.f,0.f,0.f,0.f}, s1 = {0.f,0.f,0.f,0.f};
#pragma unroll
            for (int c = 0; c < 4; ++c) {
                const int x0 = ((c*4 + lg) ^ (l16 & 7)) << 3;
                short8v kh0 = *(const short8v*)&lds[KH_O + l16*128 + x0];
                short8v kl0 = *(const short8v*)&lds[KL_O + l16*128 + x0];
                short8v kh1 = *(const short8v*)&lds[KH_O + (16+l16)*128 + x0];
                short8v kl1 = *(const short8v*)&lds[KL_O + (16+l16)*128 + x0];
                s0 = __builtin_amdgcn_mfma_f32_16x16x32_bf16(kh0, qfh[c], s0, 0,0,0);
                s0 = __builtin_amdgcn_mfma_f32_16x16x32_bf16(kh0, qfl[c], s0, 0,0,0);
                s0 = __builtin_amdgcn_mfma_f32_16x16x32_bf16(kl0, qfh[c], s0, 0,0,0);
                s1 = __builtin_amdgcn_mfma_f32_16x16x32_bf16(kh1, qfh[c], s1, 0,0,0);
                s1 = __builtin_amdgcn_mfma_f32_16x16x32_bf16(kh1, qfl[c], s1, 0,0,0);
                s1 = __builtin_amdgcn_mfma_f32_16x16x32_bf16(kl1, qfh[c], s1, 0,0,0);
            }

            // ---- causal mask (last two tiles only) ----
            const int qg = q0 + wave*16 + l16;
            if (jj >= 2*qb) {
#pragma unroll
                for (int r = 0; r < 4; ++r) {
                    if (kv0 + lg*4 + r > qg)      s0[r] = -1e30f;
                    if (kv0 + 16 + lg*4 + r > qg) s1[r] = -1e30f;
                }
            }

            // ---- online softmax (q per-lane; reduce over lg via shfl) ----
            float mx = fmaxf(fmaxf(fmaxf(s0[0], s0[1]), fmaxf(s0[2], s0[3])),
                             fmaxf(fmaxf(s1[0], s1[1]), fmaxf(s1[2], s1[3])));
            mx = fmaxf(mx, __shfl_xor(mx, 16, 64));
            mx = fmaxf(mx, __shfl_xor(mx, 32, 64));
            const float newm = fmaxf(m_s, mx);
            const float alpha = __expf(m_s - newm);
            m_s = newm;
            float pA[4], pB[4];
#pragma unroll
            for (int r = 0; r < 4; ++r) {
                pA[r] = __expf(s0[r] - newm);
                pB[r] = __expf(s1[r] - newm);
            }
            float rs = (pA[0]+pA[1]+pA[2]+pA[3]) + (pB[0]+pB[1]+pB[2]+pB[3]);
            rs += __shfl_xor(rs, 16, 64);
            rs += __shfl_xor(rs, 32, 64);
            l_s = l_s * alpha + rs;
#pragma unroll
            for (int db = 0; db < 8; ++db)
#pragma unroll
                for (int r = 0; r < 4; ++r) o[db][r] *= alpha;

            // ---- redistribute P quads to B-frag kv layout, split to bf16 ----
            u16 ph[8], pl[8];
#pragma unroll
            for (int r = 0; r < 4; ++r) {
                float T1 = __shfl_xor(pA[r], 32, 64);
                float T2 = __shfl_xor(pB[r], 32, 64);
                float pv = (lg==0) ? T1 : (lg==1) ? pA[r] : (lg==2) ? pB[r] : T2;
                float Rv = __shfl_xor(pv, 16, 64);
                float X  = (lg==0) ? pA[r] : (lg==1) ? Rv : (lg==2) ? T2 : Rv;
                float Y  = (lg==0) ? Rv    : (lg==1) ? T1 : (lg==2) ? Rv : pB[r];
                u16 hx = f32_bf16_rne(X);
                ph[r]   = hx; pl[r]   = f32_bf16_rne(X - bf16_f32(hx));
                u16 hy = f32_bf16_rne(Y);
                ph[4+r] = hy; pl[4+r] = f32_bf16_rne(Y - bf16_f32(hy));
            }
            short8v pfh, pfl;
            pfh[0]=(short)ph[0]; pfh[1]=(short)ph[1]; pfh[2]=(short)ph[2]; pfh[3]=(short)ph[3];
            pfh[4]=(short)ph[4]; pfh[5]=(short)ph[5]; pfh[6]=(short)ph[6]; pfh[7]=(short)ph[7];
            pfl[0]=(short)pl[0]; pfl[1]=(short)pl[1]; pfl[2]=(short)pl[2]; pfl[3]=(short)pl[3];
            pfl[4]=(short)pl[4]; pfl[5]=(short)pl[5]; pfl[6]=(short)pl[6]; pfl[7]=(short)pl[7];

            // ---- PV via hardware transpose reads: O^T[d][q] ----
            PV_DB(0) PV_DB(1) PV_DB(2) PV_DB(3)
            PV_DB(4) PV_DB(5) PV_DB(6) PV_DB(7)
        }

        // ---- finalize: O^T -> (S,B,D_MODEL) f32 for out-proj ----
        const int bb = bh >> 4, hh = bh & 15;
        const float inv = 1.0f / l_s;
        const int s_row = q0 + wave*16 + l16;
        float* orow = Op + (size_t)(s_row*BATCH + bb) * D_MODEL + hh*128;
#pragma unroll
        for (int tile = 0; tile < 8; ++tile) {
            float4 w = make_float4(o[tile][0]*inv, o[tile][1]*inv,
                                   o[tile][2]*inv, o[tile][3]*inv);
            *(float4*)(orow + tile*16 + lg*4) = w;
        }
    }
}

extern "C" void kernel_launch(void* const* d_in, const int* in_sizes, int n_in,
                              void* d_out, int out_size, void* d_ws, size_t ws_size,
                              hipStream_t stream) {
    const float* x      = (const float*)d_in[0];
    const float* freqs  = (const float*)d_in[1];
    const float* W_qkv  = (const float*)d_in[2];
    const float* b_qkv  = (const float*)d_in[3];
    const float* W_o    = (const float*)d_in[4];
    const float* b_o    = (const float*)d_in[5];
    float* out = (float*)d_out;

    // ws (128 MiB): 6 bf16 planes (Qh,Ql,Kh,Kl,Vh,Vl @ 16MB) + attn f32 (32MB)
    const size_t P = (size_t)M_ROWS * D_MODEL;  // 8388608 elements
    u16* ws16 = (u16*)d_ws;
    u16 *Qh = ws16,       *Ql = ws16 + P,   *Kh = ws16 + 2*P,
        *Kl = ws16 + 3*P, *Vh = ws16 + 4*P, *Vl = ws16 + 5*P;
    float* attn = (float*)(ws16 + 6*P);

    qkv_rope_mfma<<<dim3(M_ROWS/128, QKV_N/128), 256, 0, stream>>>(
        x, W_qkv, b_qkv, freqs, Qh, Ql, Kh, Kl, Vh, Vl);
    attn_mfma<<<dim3(512), 256, 0, stream>>>(Qh, Ql, Kh, Kl, Vh, Vl, attn);
    out_proj_mfma<<<dim3(M_ROWS/128, D_MODEL/128), 256, 0, stream>>>(
        attn, W_o, b_o, out);
}

// Round 6
// 730.448 us; speedup vs baseline: 4.0482x; 1.1728x over previous
//
#include <hip/hip_runtime.h>

#define D_MODEL 2048
#define N_HEADS 16
#define D_HEAD 128
#define SEQ 2048
#define BATCH 2
#define M_ROWS (SEQ*BATCH)     // 4096
#define QKV_N  (3*D_MODEL)     // 6144
#define ATTN_SCALE 0.08838834764831845f

typedef __attribute__((ext_vector_type(8))) short short8v;   // 8 bf16 (4 VGPR)
typedef __attribute__((ext_vector_type(4))) float float4v;   // 4 f32 acc
typedef __attribute__((ext_vector_type(2))) unsigned int uint2v;
typedef __attribute__((ext_vector_type(4))) unsigned int uint4v;
typedef unsigned short u16;
typedef unsigned int   u32;

__device__ __forceinline__ u16 f32_bf16_rne(float f) {
    u32 u = __float_as_uint(f);
    return (u16)((u + 0x7FFFu + ((u >> 16) & 1u)) >> 16);
}
__device__ __forceinline__ float bf16_f32(u16 h) {
    return __uint_as_float(((u32)h) << 16);
}

__device__ __forceinline__ void gll16(const void* g, void* l) {
    __builtin_amdgcn_global_load_lds(
        (const __attribute__((address_space(1))) void*)g,
        (__attribute__((address_space(3))) void*)l, 16, 0, 0);
}

// ===========================================================================
// PRE-SPLIT PATH (ws_size >= 235 MB)
// Plane layout for a RxK f32 matrix: hi/lo bf16, tiled [kt][row][32]:
//   off(row, k) = (kt*R + row)*32 + (k & 31),  kt = k >> 5
// -> per (kt, 128-row tile): 8 KB contiguous (gll-friendly), and frag reads
//    lds[row*32 + lg*8] are contiguous ds_read_b128.
// ===========================================================================
__global__ __launch_bounds__(256) void split_tiles(
    const float* __restrict__ src, u16* __restrict__ H, u16* __restrict__ L,
    const int R)
{
    const int kt = blockIdx.x, rt = blockIdx.y, t = threadIdx.x;
#pragma unroll
    for (int i = 0; i < 2; ++i) {
        const int s = i*256 + t;
        const int r = s >> 2, sub = s & 3;
        const float* p = src + (size_t)(rt*128 + r)*D_MODEL + kt*32 + sub*8;
        float4 v0 = ((const float4*)p)[0];
        float4 v1 = ((const float4*)p)[1];
        float vv[8] = {v0.x, v0.y, v0.z, v0.w, v1.x, v1.y, v1.z, v1.w};
        u16 hh[8], ll[8];
#pragma unroll
        for (int j = 0; j < 8; ++j) {
            hh[j] = f32_bf16_rne(vv[j]);
            ll[j] = f32_bf16_rne(vv[j] - bf16_f32(hh[j]));
        }
        const size_t off = ((size_t)kt*R + rt*128 + r)*32 + sub*8;
        *(uint4*)&H[off] = *(uint4*)hh;
        *(uint4*)&L[off] = *(uint4*)ll;
    }
}

// bf16x3 GEMM mainloop on pre-split planes. BK=32, 64 k-tiles, 4 waves,
// each wave 64x64 (4x4 frags of 16x16x32). Staging = pure global_load_lds.
__device__ __forceinline__ void ps_mainloop(
    const u16* __restrict__ Ah, const u16* __restrict__ Al,
    const u16* __restrict__ Bh, const u16* __restrict__ Bl,
    const int Mrows, const int Nrows, const int m0, const int n0,
    u16* lds, float4v (&acc)[4][4])
{
    const int t = threadIdx.x;
    const int lane = t & 63, wave = t >> 6;
    const int l16 = lane & 15, lg = lane >> 4;
    const int wm = wave >> 1, wn = wave & 1;
    u16* LAh = lds;          u16* LAl = lds + 4096;
    u16* LBh = lds + 8192;   u16* LBl = lds + 12288;
    const int ch0 = wave * 2;

    for (int kt = 0; kt < 64; ++kt) {
        __syncthreads();   // previous iter's frag reads done
        const size_t aoff = ((size_t)kt*Mrows + m0)*32;
        const size_t boff = ((size_t)kt*Nrows + n0)*32;
#pragma unroll
        for (int i = 0; i < 2; ++i) {
            const int ch = ch0 + i;
            const int go = ch*512 + lane*8;
            gll16(Ah + aoff + go, &LAh[ch*512]);
            gll16(Al + aoff + go, &LAl[ch*512]);
            gll16(Bh + boff + go, &LBh[ch*512]);
            gll16(Bl + boff + go, &LBl[ch*512]);
        }
        __syncthreads();   // compiler drains vmcnt(0) before this barrier

        short8v bh[4], bl[4];
#pragma unroll
        for (int fn = 0; fn < 4; ++fn) {
            const int rb = (wn*64 + fn*16 + l16)*32 + lg*8;
            bh[fn] = *(const short8v*)&LBh[rb];
            bl[fn] = *(const short8v*)&LBl[rb];
        }
#pragma unroll
        for (int fm = 0; fm < 4; ++fm) {
            const int ra = (wm*64 + fm*16 + l16)*32 + lg*8;
            short8v ah = *(const short8v*)&LAh[ra];
            short8v al = *(const short8v*)&LAl[ra];
#pragma unroll
            for (int fn = 0; fn < 4; ++fn) {
                acc[fm][fn] = __builtin_amdgcn_mfma_f32_16x16x32_bf16(ah, bh[fn], acc[fm][fn], 0,0,0);
                acc[fm][fn] = __builtin_amdgcn_mfma_f32_16x16x32_bf16(ah, bl[fn], acc[fm][fn], 0,0,0);
                acc[fm][fn] = __builtin_amdgcn_mfma_f32_16x16x32_bf16(al, bh[fn], acc[fm][fn], 0,0,0);
            }
        }
    }
}

__global__ __launch_bounds__(256, 3) void qkv_ps(
    const u16* __restrict__ Xh, const u16* __restrict__ Xl,
    const u16* __restrict__ Wh, const u16* __restrict__ Wl,
    const float* __restrict__ bias, const float* __restrict__ freqs,
    u16* __restrict__ Qh, u16* __restrict__ Ql,
    u16* __restrict__ Kh, u16* __restrict__ Kl,
    u16* __restrict__ Vh, u16* __restrict__ Vl)
{
    __shared__ u16 lds[16384];
    const int m0 = blockIdx.x*128, n0 = blockIdx.y*128;
    float4v acc[4][4];
#pragma unroll
    for (int i = 0; i < 4; ++i)
#pragma unroll
        for (int j = 0; j < 4; ++j)
#pragma unroll
            for (int r = 0; r < 4; ++r) acc[i][j][r] = 0.f;

    ps_mainloop(Xh, Xl, Wh, Wl, M_ROWS, QKV_N, m0, n0, lds, acc);

    const int t = threadIdx.x;
    const int lane = t & 63, wave = t >> 6;
    const int l16 = lane & 15, lg = lane >> 4;
    const int wm = wave >> 1, wn = wave & 1;
    const int sec = n0 >> 11;
    u16* __restrict__ hb = (sec == 0) ? Qh : ((sec == 1) ? Kh : Vh);
    u16* __restrict__ lb = (sec == 0) ? Ql : ((sec == 1) ? Kl : Vl);
#pragma unroll
    for (int fn = 0; fn < 4; ++fn) {
        const int n = n0 + wn*64 + fn*16 + l16;
        const float bn = bias[n];
        const int d = n & 127, hd = (n >> 7) & 15;
#pragma unroll
        for (int fm = 0; fm < 4; ++fm) {
#pragma unroll
            for (int r = 0; r < 4; ++r) {
                const int mrow = m0 + wm*64 + fm*16 + lg*4 + r;
                const int s = mrow >> 1, bb = mrow & 1;
                float v = acc[fm][fn][r] + bn;
                float outv;
                if (sec == 2) {
                    outv = v;
                } else {
                    float partner = __shfl_xor(v, 1, 64);
                    float fr = freqs[(size_t)s * 64 + (d >> 1)];
                    float sn, cs;
                    sincosf(fr, &sn, &cs);
                    outv = (n & 1) ? (partner*sn + v*cs) : (v*cs - partner*sn);
                    if (sec == 0) outv *= ATTN_SCALE;
                }
                size_t off = (((size_t)(bb*N_HEADS + hd) * SEQ) + s) * D_HEAD + d;
                u16 h = f32_bf16_rne(outv);
                hb[off] = h;
                lb[off] = f32_bf16_rne(outv - bf16_f32(h));
            }
        }
    }
}

__global__ __launch_bounds__(256, 3) void out_ps(
    const u16* __restrict__ Aph, const u16* __restrict__ Apl,
    const u16* __restrict__ Wh, const u16* __restrict__ Wl,
    const float* __restrict__ bias, float* __restrict__ Out)
{
    __shared__ u16 lds[16384];
    const int m0 = blockIdx.x*128, n0 = blockIdx.y*128;
    float4v acc[4][4];
#pragma unroll
    for (int i = 0; i < 4; ++i)
#pragma unroll
        for (int j = 0; j < 4; ++j)
#pragma unroll
            for (int r = 0; r < 4; ++r) acc[i][j][r] = 0.f;

    ps_mainloop(Aph, Apl, Wh, Wl, M_ROWS, D_MODEL, m0, n0, lds, acc);

    const int t = threadIdx.x;
    const int lane = t & 63, wave = t >> 6;
    const int l16 = lane & 15, lg = lane >> 4;
    const int wm = wave >> 1, wn = wave & 1;
#pragma unroll
    for (int fn = 0; fn < 4; ++fn) {
        const int n = n0 + wn*64 + fn*16 + l16;
        const float bn = bias[n];
#pragma unroll
        for (int fm = 0; fm < 4; ++fm) {
#pragma unroll
            for (int r = 0; r < 4; ++r) {
                const int mrow = m0 + wm*64 + fm*16 + lg*4 + r;
                Out[(size_t)mrow * D_MODEL + n] = acc[fm][fn][r] + bn;
            }
        }
    }
}

// ===========================================================================
// FALLBACK PATH GEMMs (R5, validated): in-loop bf16x3 split
// ===========================================================================
#define STAGE_SPLIT(vv, sH, sL)                                              \
    {                                                                        \
        _Pragma("unroll")                                                    \
        for (int q = 0; q < 4; ++q) {                                        \
            float4 v = vv[q];                                                \
            int off = ((half*2 + (q>>1))*128 + row)*8 + (q&1)*4;             \
            u16 h0 = f32_bf16_rne(v.x), h1 = f32_bf16_rne(v.y),              \
                h2 = f32_bf16_rne(v.z), h3 = f32_bf16_rne(v.w);              \
            ushort4 hv = make_ushort4(h0, h1, h2, h3);                       \
            ushort4 lv = make_ushort4(f32_bf16_rne(v.x - bf16_f32(h0)),      \
                                      f32_bf16_rne(v.y - bf16_f32(h1)),      \
                                      f32_bf16_rne(v.z - bf16_f32(h2)),      \
                                      f32_bf16_rne(v.w - bf16_f32(h3)));     \
            *(ushort4*)&sH[off] = hv;                                        \
            *(ushort4*)&sL[off] = lv;                                        \
        }                                                                    \
    }

#define GEMM_PROLOGUE()                                                      \
    __shared__ u16 sAh[4*128*8], sAl[4*128*8], sBh[4*128*8], sBl[4*128*8];   \
    const int t = threadIdx.x;                                               \
    const int m0 = blockIdx.x * 128, n0 = blockIdx.y * 128;                  \
    const int row = t >> 1, half = t & 1;                                    \
    const int lane = t & 63, wave = t >> 6;                                  \
    const int wm = wave >> 1, wn = wave & 1;                                 \
    const int l16 = lane & 15, lg = lane >> 4;                               \
    float4v acc[4][4];                                                       \
    _Pragma("unroll")                                                        \
    for (int i = 0; i < 4; ++i)                                              \
        _Pragma("unroll")                                                    \
        for (int j = 0; j < 4; ++j)                                          \
            _Pragma("unroll")                                                 \
            for (int r = 0; r < 4; ++r) acc[i][j][r] = 0.f;

#define GEMM_MAINLOOP(Aptr, Bptr)                                            \
    const float* Arow = (Aptr) + (size_t)(m0 + row) * D_MODEL + half*16;     \
    const float* Brow = (Bptr) + (size_t)(n0 + row) * D_MODEL + half*16;     \
    float4 pa[4], pb[4];                                                     \
    _Pragma("unroll")                                                        \
    for (int q = 0; q < 4; ++q) {                                            \
        pa[q] = ((const float4*)Arow)[q];                                    \
        pb[q] = ((const float4*)Brow)[q];                                    \
    }                                                                        \
    for (int kt = 0; kt < D_MODEL/32; ++kt) {                                \
        if (kt) __syncthreads();                                             \
        STAGE_SPLIT(pa, sAh, sAl);                                           \
        STAGE_SPLIT(pb, sBh, sBl);                                           \
        if (kt < D_MODEL/32 - 1) {                                           \
            Arow += 32; Brow += 32;                                          \
            _Pragma("unroll")                                                \
            for (int q = 0; q < 4; ++q) {                                    \
                pa[q] = ((const float4*)Arow)[q];                            \
                pb[q] = ((const float4*)Brow)[q];                            \
            }                                                                \
        }                                                                    \
        __syncthreads();                                                     \
        const int abase = lg*128 + wm*64 + l16;                              \
        const int bbase = lg*128 + wn*64 + l16;                              \
        short8v bh[4], bl[4];                                                \
        _Pragma("unroll")                                                    \
        for (int fn = 0; fn < 4; ++fn) {                                     \
            bh[fn] = ((const short8v*)sBh)[bbase + fn*16];                   \
            bl[fn] = ((const short8v*)sBl)[bbase + fn*16];                   \
        }                                                                    \
        _Pragma("unroll")                                                    \
        for (int fm = 0; fm < 4; ++fm) {                                     \
            short8v ah = ((const short8v*)sAh)[abase + fm*16];               \
            short8v al = ((const short8v*)sAl)[abase + fm*16];               \
            _Pragma("unroll")                                                \
            for (int fn = 0; fn < 4; ++fn) {                                 \
                acc[fm][fn] = __builtin_amdgcn_mfma_f32_16x16x32_bf16(       \
                    ah, bh[fn], acc[fm][fn], 0, 0, 0);                       \
                acc[fm][fn] = __builtin_amdgcn_mfma_f32_16x16x32_bf16(       \
                    ah, bl[fn], acc[fm][fn], 0, 0, 0);                       \
                acc[fm][fn] = __builtin_amdgcn_mfma_f32_16x16x32_bf16(       \
                    al, bh[fn], acc[fm][fn], 0, 0, 0);                       \
            }                                                                \
        }                                                                    \
    }

__global__ __launch_bounds__(256, 2) void qkv_rope_mfma(
    const float* __restrict__ X, const float* __restrict__ W,
    const float* __restrict__ bias, const float* __restrict__ freqs,
    u16* __restrict__ Qh, u16* __restrict__ Ql,
    u16* __restrict__ Kh, u16* __restrict__ Kl,
    u16* __restrict__ Vh, u16* __restrict__ Vl)
{
    GEMM_PROLOGUE();
    GEMM_MAINLOOP(X, W);
    const int sec = n0 >> 11;
    u16* __restrict__ hb = (sec == 0) ? Qh : ((sec == 1) ? Kh : Vh);
    u16* __restrict__ lb = (sec == 0) ? Ql : ((sec == 1) ? Kl : Vl);
#pragma unroll
    for (int fn = 0; fn < 4; ++fn) {
        const int n = n0 + wn*64 + fn*16 + l16;
        const float bn = bias[n];
        const int d = n & 127, hd = (n >> 7) & 15;
#pragma unroll
        for (int fm = 0; fm < 4; ++fm) {
#pragma unroll
            for (int r = 0; r < 4; ++r) {
                const int mrow = m0 + wm*64 + fm*16 + lg*4 + r;
                const int s = mrow >> 1, bb = mrow & 1;
                float v = acc[fm][fn][r] + bn;
                float outv;
                if (sec == 2) {
                    outv = v;
                } else {
                    float partner = __shfl_xor(v, 1, 64);
                    float fr = freqs[(size_t)s * 64 + (d >> 1)];
                    float sn, cs;
                    sincosf(fr, &sn, &cs);
                    outv = (n & 1) ? (partner*sn + v*cs) : (v*cs - partner*sn);
                    if (sec == 0) outv *= ATTN_SCALE;
                }
                size_t off = (((size_t)(bb*N_HEADS + hd) * SEQ) + s) * D_HEAD + d;
                u16 h = f32_bf16_rne(outv);
                hb[off] = h;
                lb[off] = f32_bf16_rne(outv - bf16_f32(h));
            }
        }
    }
}

__global__ __launch_bounds__(256, 2) void out_proj_mfma(
    const float* __restrict__ A, const float* __restrict__ W,
    const float* __restrict__ bias, float* __restrict__ Out)
{
    GEMM_PROLOGUE();
    GEMM_MAINLOOP(A, W);
#pragma unroll
    for (int fn = 0; fn < 4; ++fn) {
        const int n = n0 + wn*64 + fn*16 + l16;
        const float bn = bias[n];
#pragma unroll
        for (int fm = 0; fm < 4; ++fm) {
#pragma unroll
            for (int r = 0; r < 4; ++r) {
                const int mrow = m0 + wm*64 + fm*16 + lg*4 + r;
                Out[(size_t)mrow * D_MODEL + n] = acc[fm][fn][r] + bn;
            }
        }
    }
}

// ===========================================================================
// Attention (bf16x3 MFMA, validated R5 core).
// MODE 0: epilogue writes f32 flat (S,B,D_MODEL)       [fallback path]
// MODE 1: epilogue writes hi/lo bf16 tiled A-planes    [pre-split path]
// ===========================================================================
#define QH_O 0
#define QL_O 8192
#define KH_O 16384
#define KL_O 20480
#define VH_O 24576
#define VL_O 28672

#define PV_DB(DB)                                                            \
    {                                                                        \
        uint2v th0, th1, tl0, tl1;                                           \
        u32 aH = vbH + DB*1024, aL = vbL + DB*1024;                          \
        asm volatile("ds_read_b64_tr_b16 %0, %4\n\t"                         \
                     "ds_read_b64_tr_b16 %1, %4 offset:128\n\t"              \
                     "ds_read_b64_tr_b16 %2, %5\n\t"                         \
                     "ds_read_b64_tr_b16 %3, %5 offset:128\n\t"              \
                     "s_waitcnt lgkmcnt(0)"                                  \
                     : "=v"(th0), "=v"(th1), "=v"(tl0), "=v"(tl1)            \
                     : "v"(aH), "v"(aL));                                    \
        __builtin_amdgcn_sched_barrier(0);                                   \
        uint4v uh; uh.x = th0.x; uh.y = th0.y; uh.z = th1.x; uh.w = th1.y;   \
        uint4v ul; ul.x = tl0.x; ul.y = tl0.y; ul.z = tl1.x; ul.w = tl1.y;   \
        short8v vfh = __builtin_bit_cast(short8v, uh);                       \
        short8v vfl = __builtin_bit_cast(short8v, ul);                       \
        o[DB] = __builtin_amdgcn_mfma_f32_16x16x32_bf16(vfh, pfh, o[DB], 0,0,0); \
        o[DB] = __builtin_amdgcn_mfma_f32_16x16x32_bf16(vfh, pfl, o[DB], 0,0,0); \
        o[DB] = __builtin_amdgcn_mfma_f32_16x16x32_bf16(vfl, pfh, o[DB], 0,0,0); \
    }

template<int MODE>
__global__ __launch_bounds__(256, 2) void attn_mfma_t(
    const u16* __restrict__ Qh_g, const u16* __restrict__ Ql_g,
    const u16* __restrict__ Kh_g, const u16* __restrict__ Kl_g,
    const u16* __restrict__ Vh_g, const u16* __restrict__ Vl_g,
    float* __restrict__ Op, u16* __restrict__ AH, u16* __restrict__ AL)
{
    __shared__ __align__(16) u16 lds[32768];   // 64 KiB

    const int t = threadIdx.x;
    const int lane = t & 63, wave = t >> 6;
    const int l16 = lane & 15, lg = lane >> 4;

    const int bid = blockIdx.x;
    const int bh = (bid & 7) * 4 + ((bid >> 3) >> 4);
    const int pairid = (bid >> 3) & 15;
    const size_t ho = (size_t)bh * SEQ * D_HEAD;

    const int skv = t >> 3;
    const int sdb = t & 7;

    const u32 ldsb = (u32)(uintptr_t)lds;
    const u32 vbH = ldsb + VH_O*2 + lg*256 + l16*8;
    const u32 vbL = ldsb + VL_O*2 + lg*256 + l16*8;

    for (int pass = 0; pass < 2; ++pass) {
        const int qb = pass ? (31 - pairid) : pairid;
        const int q0 = qb * 64;
        __syncthreads();
#pragma unroll
        for (int i = 0; i < 2; ++i) {
            int task = i*256 + t;
            int qr = task >> 3, db = task & 7;
            size_t gsrc = ho + (size_t)(q0 + qr)*128 + db*16;
            uint4 h0 = *(const uint4*)(Qh_g + gsrc);
            uint4 h1 = *(const uint4*)(Qh_g + gsrc + 8);
            uint4 L0 = *(const uint4*)(Ql_g + gsrc);
            uint4 L1 = *(const uint4*)(Ql_g + gsrc + 8);
            *(uint4*)&lds[QH_O + ((db*2  )*64 + qr)*8] = h0;
            *(uint4*)&lds[QH_O + ((db*2+1)*64 + qr)*8] = h1;
            *(uint4*)&lds[QL_O + ((db*2  )*64 + qr)*8] = L0;
            *(uint4*)&lds[QL_O + ((db*2+1)*64 + qr)*8] = L1;
        }
        __syncthreads();
        short8v qfh[4], qfl[4];
#pragma unroll
        for (int c = 0; c < 4; ++c) {
            int g = c*4 + lg;
            qfh[c] = *(const short8v*)&lds[QH_O + (g*64 + wave*16 + l16)*8];
            qfl[c] = *(const short8v*)&lds[QL_O + (g*64 + wave*16 + l16)*8];
        }

        float4v o[8];
#pragma unroll
        for (int db = 0; db < 8; ++db)
#pragma unroll
            for (int r = 0; r < 4; ++r) o[db][r] = 0.f;
        float m_s = -1e30f, l_s = 0.f;

        const int jjmax = 2*qb + 1;
        for (int jj = 0; jj <= jjmax; ++jj) {
            const int kv0 = jj * 32;
            __syncthreads();
            {
                size_t gk = ho + (size_t)(kv0 + skv)*128 + sdb*16;
                uint4 kh0 = *(const uint4*)(Kh_g + gk);
                uint4 kh1 = *(const uint4*)(Kh_g + gk + 8);
                uint4 kl0 = *(const uint4*)(Kl_g + gk);
                uint4 kl1 = *(const uint4*)(Kl_g + gk + 8);
                uint4 vh0 = *(const uint4*)(Vh_g + gk);
                uint4 vh1 = *(const uint4*)(Vh_g + gk + 8);
                uint4 vl0 = *(const uint4*)(Vl_g + gk);
                uint4 vl1 = *(const uint4*)(Vl_g + gk + 8);
                const int k7 = skv & 7;
                const int g0 = sdb*2, g1 = sdb*2 + 1;
                *(uint4*)&lds[KH_O + skv*128 + ((g0^k7)<<3)] = kh0;
                *(uint4*)&lds[KH_O + skv*128 + ((g1^k7)<<3)] = kh1;
                *(uint4*)&lds[KL_O + skv*128 + ((g0^k7)<<3)] = kl0;
                *(uint4*)&lds[KL_O + skv*128 + ((g1^k7)<<3)] = kl1;
                const int vreg = (sdb*8 + (skv>>2))*64 + (skv&3)*16;
                *(uint4*)&lds[VH_O + vreg]     = vh0;
                *(uint4*)&lds[VH_O + vreg + 8] = vh1;
                *(uint4*)&lds[VL_O + vreg]     = vl0;
                *(uint4*)&lds[VL_O + vreg + 8] = vl1;
            }
            __syncthreads();

            float4v s0 = {0.f,0.f,0.f,0.f}, s1 = {0.f,0.f,0.f,0.f};
#pragma unroll
            for (int c = 0; c < 4; ++c) {
                const int x0 = ((c*4 + lg) ^ (l16 & 7)) << 3;
                short8v kh0 = *(const short8v*)&lds[KH_O + l16*128 + x0];
                short8v kl0 = *(const short8v*)&lds[KL_O + l16*128 + x0];
                short8v kh1 = *(const short8v*)&lds[KH_O + (16+l16)*128 + x0];
                short8v kl1 = *(const short8v*)&lds[KL_O + (16+l16)*128 + x0];
                s0 = __builtin_amdgcn_mfma_f32_16x16x32_bf16(kh0, qfh[c], s0, 0,0,0);
                s0 = __builtin_amdgcn_mfma_f32_16x16x32_bf16(kh0, qfl[c], s0, 0,0,0);
                s0 = __builtin_amdgcn_mfma_f32_16x16x32_bf16(kl0, qfh[c], s0, 0,0,0);
                s1 = __builtin_amdgcn_mfma_f32_16x16x32_bf16(kh1, qfh[c], s1, 0,0,0);
                s1 = __builtin_amdgcn_mfma_f32_16x16x32_bf16(kh1, qfl[c], s1, 0,0,0);
                s1 = __builtin_amdgcn_mfma_f32_16x16x32_bf16(kl1, qfh[c], s1, 0,0,0);
            }

            const int qg = q0 + wave*16 + l16;
            if (jj >= 2*qb) {
#pragma unroll
                for (int r = 0; r < 4; ++r) {
                    if (kv0 + lg*4 + r > qg)      s0[r] = -1e30f;
                    if (kv0 + 16 + lg*4 + r > qg) s1[r] = -1e30f;
                }
            }

            float mx = fmaxf(fmaxf(fmaxf(s0[0], s0[1]), fmaxf(s0[2], s0[3])),
                             fmaxf(fmaxf(s1[0], s1[1]), fmaxf(s1[2], s1[3])));
            mx = fmaxf(mx, __shfl_xor(mx, 16, 64));
            mx = fmaxf(mx, __shfl_xor(mx, 32, 64));
            const float newm = fmaxf(m_s, mx);
            const float alpha = __expf(m_s - newm);
            m_s = newm;
            float pA[4], pB[4];
#pragma unroll
            for (int r = 0; r < 4; ++r) {
                pA[r] = __expf(s0[r] - newm);
                pB[r] = __expf(s1[r] - newm);
            }
            float rs = (pA[0]+pA[1]+pA[2]+pA[3]) + (pB[0]+pB[1]+pB[2]+pB[3]);
            rs += __shfl_xor(rs, 16, 64);
            rs += __shfl_xor(rs, 32, 64);
            l_s = l_s * alpha + rs;
#pragma unroll
            for (int db = 0; db < 8; ++db)
#pragma unroll
                for (int r = 0; r < 4; ++r) o[db][r] *= alpha;

            u16 ph[8], pl[8];
#pragma unroll
            for (int r = 0; r < 4; ++r) {
                float T1 = __shfl_xor(pA[r], 32, 64);
                float T2 = __shfl_xor(pB[r], 32, 64);
                float pv = (lg==0) ? T1 : (lg==1) ? pA[r] : (lg==2) ? pB[r] : T2;
                float Rv = __shfl_xor(pv, 16, 64);
                float X  = (lg==0) ? pA[r] : (lg==1) ? Rv : (lg==2) ? T2 : Rv;
                float Y  = (lg==0) ? Rv    : (lg==1) ? T1 : (lg==2) ? Rv : pB[r];
                u16 hx = f32_bf16_rne(X);
                ph[r]   = hx; pl[r]   = f32_bf16_rne(X - bf16_f32(hx));
                u16 hy = f32_bf16_rne(Y);
                ph[4+r] = hy; pl[4+r] = f32_bf16_rne(Y - bf16_f32(hy));
            }
            short8v pfh, pfl;
            pfh[0]=(short)ph[0]; pfh[1]=(short)ph[1]; pfh[2]=(short)ph[2]; pfh[3]=(short)ph[3];
            pfh[4]=(short)ph[4]; pfh[5]=(short)ph[5]; pfh[6]=(short)ph[6]; pfh[7]=(short)ph[7];
            pfl[0]=(short)pl[0]; pfl[1]=(short)pl[1]; pfl[2]=(short)pl[2]; pfl[3]=(short)pl[3];
            pfl[4]=(short)pl[4]; pfl[5]=(short)pl[5]; pfl[6]=(short)pl[6]; pfl[7]=(short)pl[7];

            PV_DB(0) PV_DB(1) PV_DB(2) PV_DB(3)
            PV_DB(4) PV_DB(5) PV_DB(6) PV_DB(7)
        }

        const int bb = bh >> 4, hh = bh & 15;
        const float inv = 1.0f / l_s;
        const int s_row = q0 + wave*16 + l16;
        if constexpr (MODE == 0) {
            float* orow = Op + (size_t)(s_row*BATCH + bb) * D_MODEL + hh*128;
#pragma unroll
            for (int tile = 0; tile < 8; ++tile) {
                float4 w = make_float4(o[tile][0]*inv, o[tile][1]*inv,
                                       o[tile][2]*inv, o[tile][3]*inv);
                *(float4*)(orow + tile*16 + lg*4) = w;
            }
        } else {
            const int m = s_row*BATCH + bb;
#pragma unroll
            for (int tile = 0; tile < 8; ++tile) {
                const int kt = hh*4 + (tile >> 1);
                const size_t off = ((size_t)kt*M_ROWS + m)*32 + (tile & 1)*16 + lg*4;
                u16 hh4[4], ll4[4];
#pragma unroll
                for (int r = 0; r < 4; ++r) {
                    float w = o[tile][r]*inv;
                    hh4[r] = f32_bf16_rne(w);
                    ll4[r] = f32_bf16_rne(w - bf16_f32(hh4[r]));
                }
                *(ushort4*)&AH[off] = make_ushort4(hh4[0], hh4[1], hh4[2], hh4[3]);
                *(ushort4*)&AL[off] = make_ushort4(ll4[0], ll4[1], ll4[2], ll4[3]);
            }
        }
    }
}

extern "C" void kernel_launch(void* const* d_in, const int* in_sizes, int n_in,
                              void* d_out, int out_size, void* d_ws, size_t ws_size,
                              hipStream_t stream) {
    const float* x      = (const float*)d_in[0];
    const float* freqs  = (const float*)d_in[1];
    const float* W_qkv  = (const float*)d_in[2];
    const float* b_qkv  = (const float*)d_in[3];
    const float* W_o    = (const float*)d_in[4];
    const float* b_o    = (const float*)d_in[5];
    float* out = (float*)d_out;

    const size_t PX = (size_t)M_ROWS * D_MODEL;   // 8388608
    const size_t PW = (size_t)QKV_N  * D_MODEL;   // 12582912
    const size_t PO = (size_t)D_MODEL* D_MODEL;   // 4194304
    u16* ws16 = (u16*)d_ws;

    if (ws_size >= (10*PX + 2*PW + 2*PO) * sizeof(u16)) {   // 234,881,024 B
        u16* Xh  = ws16;            u16* Xl  = Xh  + PX;
        u16* Wqh = Xl + PX;         u16* Wql = Wqh + PW;
        u16* Woh = Wql + PW;        u16* Wol = Woh + PO;
        u16* Qh  = Wol + PO;        u16* Ql  = Qh + PX;
        u16* Kh  = Ql + PX;         u16* Kl  = Kh + PX;
        u16* Vh  = Kl + PX;         u16* Vl  = Vh + PX;
        u16* Ahp = Vl + PX;         u16* Alp = Ahp + PX;

        split_tiles<<<dim3(64, M_ROWS/128), 256, 0, stream>>>(x,     Xh,  Xl,  M_ROWS);
        split_tiles<<<dim3(64, QKV_N/128),  256, 0, stream>>>(W_qkv, Wqh, Wql, QKV_N);
        split_tiles<<<dim3(64, D_MODEL/128),256, 0, stream>>>(W_o,   Woh, Wol, D_MODEL);
        qkv_ps<<<dim3(M_ROWS/128, QKV_N/128), 256, 0, stream>>>(
            Xh, Xl, Wqh, Wql, b_qkv, freqs, Qh, Ql, Kh, Kl, Vh, Vl);
        attn_mfma_t<1><<<dim3(512), 256, 0, stream>>>(
            Qh, Ql, Kh, Kl, Vh, Vl, nullptr, Ahp, Alp);
        out_ps<<<dim3(M_ROWS/128, D_MODEL/128), 256, 0, stream>>>(
            Ahp, Alp, Woh, Wol, b_o, out);
    } else {
        // Fallback (R5 validated): in-loop split GEMMs, f32 attn buffer
        u16 *Qh = ws16,       *Ql = ws16 + PX,   *Kh = ws16 + 2*PX,
            *Kl = ws16 + 3*PX, *Vh = ws16 + 4*PX, *Vl = ws16 + 5*PX;
        float* attn = (float*)(ws16 + 6*PX);

        qkv_rope_mfma<<<dim3(M_ROWS/128, QKV_N/128), 256, 0, stream>>>(
            x, W_qkv, b_qkv, freqs, Qh, Ql, Kh, Kl, Vh, Vl);
        attn_mfma_t<0><<<dim3(512), 256, 0, stream>>>(
            Qh, Ql, Kh, Kl, Vh, Vl, attn, nullptr, nullptr);
        out_proj_mfma<<<dim3(M_ROWS/128, D_MODEL/128), 256, 0, stream>>>(
            attn, W_o, b_o, out);
    }
}